// Round 12
// baseline (482.701 us; speedup 1.0000x reference)
//
#include <hip/hip_runtime.h>
#include <hip/hip_bf16.h>

// B=16384 W=5 L=20 E=50 V=100000 C=128 H=4096 O=50
// ha  = bf16 [16384][256] (K: 250 data + [250]=1.0 bias slot + pad)  ws+0    (8 MB)
// wb  = bf16 [4096][256]  (fc1_w as [N][K], [n][250]=fc1_b[n])       ws+8M   (2 MB)
// w2b = bf16 [64][4096]   (fc2_w padded to 64 rows)                  ws+10M  (0.5 MB)
// gt  = fp32 [128][156]                                              ws+16M  (78 KB)
// h is NEVER materialized: fused fc1+tanh+fc2+softmax kernel.

typedef __attribute__((ext_vector_type(8))) short short8;
typedef __attribute__((ext_vector_type(4))) float float4v;

__device__ inline short bf16b(float f) {
    __hip_bfloat16 h = __float2bfloat16(f);
    return *reinterpret_cast<short*>(&h);
}
__device__ inline uint packbf2(float a, float b) {
    return (uint)(ushort)bf16b(a) | ((uint)(ushort)bf16b(b) << 16);
}

// ---------------------------------------------------------------------------
// wb[n][k]: k<250 -> fc1_w[n][k]; k==250 -> fc1_b[n] (bias fold); else 0.
// ---------------------------------------------------------------------------
__global__ void wb_kernel(const float* __restrict__ fc1_w,
                          const float* __restrict__ fc1_b,
                          __hip_bfloat16* __restrict__ wb) {
    int idx = blockIdx.x * 256 + threadIdx.x;     // n*256 + k
    int n = idx >> 8, k = idx & 255;
    float v = (k < 250) ? fc1_w[n * 250 + k] : (k == 250 ? fc1_b[n] : 0.f);
    wb[idx] = __float2bfloat16(v);
}

// ---------------------------------------------------------------------------
__global__ void w2b_kernel(const float* __restrict__ fc2_w,
                           __hip_bfloat16* __restrict__ w2b) {
    int idx = blockIdx.x * 256 + threadIdx.x;     // n*4096 + k
    int n = idx >> 12;
    w2b[idx] = __float2bfloat16(n < 50 ? fc2_w[idx] : 0.f);
}

// ---------------------------------------------------------------------------
// gt[c*156 + kk*52 + o] = sum_i char_emb[c*50+i] * conv_w[(o*50+i)*3+kk]
// ---------------------------------------------------------------------------
__global__ void gt_kernel(const float* __restrict__ char_emb,
                          const float* __restrict__ conv_w,
                          float* __restrict__ gt) {
    int idx = blockIdx.x * 256 + threadIdx.x;     // < 19200
    if (idx >= 19200) return;
    int c = idx / 150, rem = idx - c * 150;
    int kk = rem / 50, o = rem - kk * 50;
    const float* ce = char_emb + c * 50;
    const float* w  = conv_w + o * 150 + kk;
    float s = 0.f;
    #pragma unroll 10
    for (int i = 0; i < 50; ++i) s += ce[i] * w[i * 3];
    gt[c * 156 + kk * 52 + o] = s;
}

// ---------------------------------------------------------------------------
// pad cols: [250]=1.0 (bias slot), 251..255 = 0
// ---------------------------------------------------------------------------
__global__ void haPad_kernel(__hip_bfloat16* __restrict__ ha) {
    int idx = blockIdx.x * 256 + threadIdx.x;     // b*6 + j
    int b = idx / 6, j = idx - b * 6;
    ha[b * 256 + 250 + j] = __float2bfloat16(j == 0 ? 1.f : 0.f);
}

// ---------------------------------------------------------------------------
// conv via table lookup (unchanged, proven R7). Block = 512 thr = 32 words.
// ---------------------------------------------------------------------------
__global__ __launch_bounds__(512) void conv_kernel(
    const int* __restrict__ x, const int* __restrict__ wci,
    const float* __restrict__ word_emb, const float* __restrict__ conv_b,
    const float* __restrict__ gt, __hip_bfloat16* __restrict__ ha)
{
    __shared__ float Gs[19968];       // 79,872 B
    __shared__ uint  cpack[160];
    __shared__ int   xs[32];

    const int tid = threadIdx.x;
    const int gw0 = blockIdx.x * 32;

    int xr = 0;
    if (tid < 32) xr = x[gw0 + tid];

    #pragma unroll
    for (int t = 0; t < 39; ++t)
        Gs[t * 512 + tid] = gt[t * 512 + tid];

    if (tid < 32) {
        const int* crow = wci + xr * 20;
        int cid[20];
        #pragma unroll
        for (int p = 0; p < 20; ++p) cid[p] = crow[p];
        #pragma unroll
        for (int u = 0; u < 5; ++u)
            cpack[tid * 5 + u] = (uint)cid[u * 4] | ((uint)cid[u * 4 + 1] << 8)
                               | ((uint)cid[u * 4 + 2] << 16) | ((uint)cid[u * 4 + 3] << 24);
        xs[tid] = xr;
    }
    __syncthreads();

    const int lane = tid & 63;
    const int wv   = tid >> 6;
    const int t    = lane & 15;
    const int w    = lane >> 4;
    const int tc   = (t < 13) ? t : 12;
    const int widx = wv * 4 + w;

    uint cw[5];
    #pragma unroll
    for (int u = 0; u < 5; ++u) cw[u] = cpack[widx * 5 + u];
    int ca[20];
    #pragma unroll
    for (int p = 0; p < 20; ++p)
        ca[p] = (int)((cw[p >> 2] >> ((p & 3) * 8)) & 0xFF) * 156;

    const int tc4 = tc * 4;
    float4 mx;
    {
        float4 v = *(const float4*)&Gs[ca[0] + 52 + tc4];
        float4 u = *(const float4*)&Gs[ca[1] + 104 + tc4];
        mx.x = v.x + u.x; mx.y = v.y + u.y; mx.z = v.z + u.z; mx.w = v.w + u.w;
    }
    #pragma unroll
    for (int l = 1; l < 19; ++l) {
        float4 v = *(const float4*)&Gs[ca[l] + 52 + tc4];
        float4 a = *(const float4*)&Gs[ca[l - 1] + tc4];
        float4 b = *(const float4*)&Gs[ca[l + 1] + 104 + tc4];
        float vx = v.x + a.x + b.x, vy = v.y + a.y + b.y;
        float vz = v.z + a.z + b.z, vw = v.w + a.w + b.w;
        mx.x = fmaxf(mx.x, vx); mx.y = fmaxf(mx.y, vy);
        mx.z = fmaxf(mx.z, vz); mx.w = fmaxf(mx.w, vw);
    }
    {
        float4 v = *(const float4*)&Gs[ca[19] + 52 + tc4];
        float4 a = *(const float4*)&Gs[ca[18] + tc4];
        mx.x = fmaxf(mx.x, v.x + a.x); mx.y = fmaxf(mx.y, v.y + a.y);
        mx.z = fmaxf(mx.z, v.z + a.z); mx.w = fmaxf(mx.w, v.w + a.w);
    }

    const int xid = xs[widx];
    const float* wer = word_emb + (size_t)xid * 50 + tc4;
    float2 wea = *(const float2*)wer;
    float2 web = make_float2(0.f, 0.f);
    float2 cba = *(const float2*)(conv_b + tc4);
    float2 cbb = make_float2(0.f, 0.f);
    if (tc < 12) {
        web = *(const float2*)(wer + 2);
        cbb = *(const float2*)(conv_b + tc4 + 2);
    }
    const int gw = gw0 + widx, b = gw / 5, wp = gw - b * 5;
    __hip_bfloat16* dst = ha + b * 256 + wp * 50 + tc4;
    uint lo = packbf2(mx.x + cba.x + wea.x, mx.y + cba.y + wea.y);
    if (t < 12) {
        uint hi = packbf2(mx.z + cbb.x + web.x, mx.w + cbb.y + web.y);
        *(uint*)dst = lo;
        *((uint*)dst + 1) = hi;
    } else if (t == 12) {
        *(uint*)dst = lo;
    }
}

// ---------------------------------------------------------------------------
// FUSED fc1+tanh+fc2+softmax. Block = 64 rows, 512 thr (8 waves = wr[0..3] x
// wc[0..1]). fc1 operand-swapped: A=wb (cols), B=ha (rows) so each thread's
// C-tile holds 4 consecutive h-cols of one row -> single ds_write_b64 into
// fc2 A-fragment layout. K-fold bias. fc2 accumulates over 32 col-chunks.
// ---------------------------------------------------------------------------
__global__ __launch_bounds__(512) void fused_kernel(
    const __hip_bfloat16* __restrict__ ha, const __hip_bfloat16* __restrict__ wb,
    const __hip_bfloat16* __restrict__ w2b, const float* __restrict__ fc2_b,
    float* __restrict__ out)
{
    __shared__ short8 As[2048];     // ha rows frag-linear [(rt*8+ks)*64+lane], 32 KB
    __shared__ short8 Pf[1024];     // P chunk as fc2 A-frags [(wr*4+ks)*64+lane], 16 KB
    __shared__ float  Ls[64 * 68];  // logits, 17 KB

    const int tid  = threadIdx.x;
    const int lane = tid & 63;
    const int wv   = tid >> 6;
    const int wr = wv >> 1, wc = wv & 1;
    const int m = lane & 15, q = lane >> 4;
    const int r0 = blockIdx.x * 64;

    // ---- stage ha rows once (K=256), proven frag-linear layout ----
    #pragma unroll
    for (int s = 0; s < 4; ++s) {
        const int seg = s * 512 + tid;            // 0..2047
        const int grp = seg >> 6;                 // rt*8 + ks
        const int rt = grp >> 3, ks = grp & 7;
        const int l = seg & 63;
        const int lq = l >> 4, lm = l & 15;
        As[seg] = *(const short8*)(ha + (size_t)(r0 + rt * 16 + lm) * 256
                                      + ks * 32 + lq * 8);
    }
    __syncthreads();

    float4v acc2[2] = {};

    for (int ch = 0; ch < 32; ++ch) {
        const int c0 = ch * 128;

        // ---- fc1: D[colTile t][rowTile wr], t = wc*4+mt ----
        float4v acc[4] = {};
        #pragma unroll
        for (int ks = 0; ks < 8; ++ks) {
            short8 bv = As[(wr * 8 + ks) * 64 + lane];
            #pragma unroll
            for (int mt = 0; mt < 4; ++mt) {
                const int t = wc * 4 + mt;
                short8 av = *(const short8*)(wb + (size_t)(c0 + t * 16 + m) * 256
                                                + ks * 32 + q * 8);
                acc[mt] = __builtin_amdgcn_mfma_f32_16x16x32_bf16(av, bv, acc[mt], 0, 0, 0);
            }
        }
        __syncthreads();   // prior chunk's fc2 Pf reads complete

        // ---- tanh + pack into fc2 A-frag layout (one b64 per tile) ----
        #pragma unroll
        for (int mt = 0; mt < 4; ++mt) {
            const int t = wc * 4 + mt;
            float tv[4];
            #pragma unroll
            for (int r = 0; r < 4; ++r) {
                float v = acc[mt][r];              // bias already folded via K
                tv[r] = 1.f - 2.f / (__expf(2.f * v) + 1.f);
            }
            const uint p0 = packbf2(tv[0], tv[1]);
            const uint p1 = packbf2(tv[2], tv[3]);
            const int seg = (wr * 4 + (t >> 1)) * 64 + ((t & 1) * 2 + (q >> 1)) * 16 + m;
            *(uint2*)((char*)&Pf[seg] + (q & 1) * 8) = make_uint2(p0, p1);
        }
        __syncthreads();   // Pf visible

        // ---- fc2: accumulate logits, A=Pf, B=w2b (direct global) ----
        #pragma unroll
        for (int ks = 0; ks < 4; ++ks) {
            short8 av = Pf[(wr * 4 + ks) * 64 + lane];
            #pragma unroll
            for (int t2 = 0; t2 < 2; ++t2) {
                short8 bv = *(const short8*)(w2b + (size_t)((wc * 2 + t2) * 16 + m) * 4096
                                                 + c0 + ks * 32 + q * 8);
                acc2[t2] = __builtin_amdgcn_mfma_f32_16x16x32_bf16(av, bv, acc2[t2], 0, 0, 0);
            }
        }
    }

    // ---- logits -> LDS (C layout: row=q*4+r, col=lane&15) ----
    #pragma unroll
    for (int t2 = 0; t2 < 2; ++t2)
        #pragma unroll
        for (int r = 0; r < 4; ++r)
            Ls[(wr * 16 + q * 4 + r) * 68 + (wc * 2 + t2) * 16 + m] = acc2[t2][r];
    __syncthreads();

    // ---- softmax: 8 rows per wave (proven shuffle pattern) ----
    #pragma unroll
    for (int rr = 0; rr < 8; ++rr) {
        const int row = wv * 8 + rr;
        float v = (lane < 50) ? Ls[row * 68 + lane] + fc2_b[lane] : -1e30f;
        float mx = v;
        for (int off = 32; off > 0; off >>= 1) mx = fmaxf(mx, __shfl_xor(mx, off));
        float e = __expf(v - mx);
        float ssum = e;
        for (int off = 32; off > 0; off >>= 1) ssum += __shfl_xor(ssum, off);
        if (lane < 50)
            out[(size_t)(r0 + row) * 50 + lane] = e / ssum;
    }
}

// ---------------------------------------------------------------------------
extern "C" void kernel_launch(void* const* d_in, const int* in_sizes, int n_in,
                              void* d_out, int out_size, void* d_ws, size_t ws_size,
                              hipStream_t stream) {
    const int*   x        = (const int*)  d_in[0];
    const int*   wci      = (const int*)  d_in[1];
    const float* word_emb = (const float*)d_in[2];
    const float* char_emb = (const float*)d_in[3];
    const float* conv_w   = (const float*)d_in[4];
    const float* conv_b   = (const float*)d_in[5];
    const float* fc1_w    = (const float*)d_in[6];
    const float* fc1_b    = (const float*)d_in[7];
    const float* fc2_w    = (const float*)d_in[8];
    const float* fc2_b    = (const float*)d_in[9];
    float* out = (float*)d_out;

    char* ws = (char*)d_ws;
    __hip_bfloat16* ha  = (__hip_bfloat16*)ws;                          // 8 MB
    __hip_bfloat16* wb  = (__hip_bfloat16*)(ws + ((size_t)8  << 20));   // 2 MB
    __hip_bfloat16* w2b = (__hip_bfloat16*)(ws + ((size_t)10 << 20));   // 0.5 MB
    float*          gtp = (float*)(ws + ((size_t)16 << 20));            // 78 KB

    wb_kernel<<<4096, 256, 0, stream>>>(fc1_w, fc1_b, wb);
    w2b_kernel<<<1024, 256, 0, stream>>>(fc2_w, w2b);
    gt_kernel<<<75, 256, 0, stream>>>(char_emb, conv_w, gtp);
    haPad_kernel<<<384, 256, 0, stream>>>(ha);
    conv_kernel<<<2560, 512, 0, stream>>>(x, wci, word_emb, conv_b, gtp, ha);
    fused_kernel<<<256, 512, 0, stream>>>(ha, wb, w2b, fc2_b, out);
}

// Round 13
// 309.069 us; speedup vs baseline: 1.5618x; 1.5618x over previous
//
#include <hip/hip_runtime.h>
#include <hip/hip_bf16.h>

// B=16384 W=5 L=20 E=50 V=100000 C=128 H=4096 O=50
// ha  = bf16 [16384][256] (K: 250 data + [250]=1.0 bias slot + pad)  ws+0    (8 MB)
// wb  = bf16 [4096][256]  (fc1_w as [N][K], [n][250]=fc1_b[n])       ws+8M   (2 MB)
// w2b = bf16 [64][4096]   (fc2_w padded to 64 rows)                  ws+10M  (0.5 MB)
// gt  = fp32 [128][156]                                              ws+16M  (78 KB)
// h never materialized. Fused kernel: 32 rows/block, 512 blocks, 33 KB LDS,
// per-chunk register prefetch of wb/w2b fragments.

typedef __attribute__((ext_vector_type(8))) short short8;
typedef __attribute__((ext_vector_type(4))) float float4v;

__device__ inline short bf16b(float f) {
    __hip_bfloat16 h = __float2bfloat16(f);
    return *reinterpret_cast<short*>(&h);
}
__device__ inline uint packbf2(float a, float b) {
    return (uint)(ushort)bf16b(a) | ((uint)(ushort)bf16b(b) << 16);
}

// ---------------------------------------------------------------------------
// wb[n][k]: k<250 -> fc1_w[n][k]; k==250 -> fc1_b[n]; else 0.
// ---------------------------------------------------------------------------
__global__ void wb_kernel(const float* __restrict__ fc1_w,
                          const float* __restrict__ fc1_b,
                          __hip_bfloat16* __restrict__ wb) {
    int idx = blockIdx.x * 256 + threadIdx.x;     // n*256 + k
    int n = idx >> 8, k = idx & 255;
    float v = (k < 250) ? fc1_w[n * 250 + k] : (k == 250 ? fc1_b[n] : 0.f);
    wb[idx] = __float2bfloat16(v);
}

// ---------------------------------------------------------------------------
__global__ void w2b_kernel(const float* __restrict__ fc2_w,
                           __hip_bfloat16* __restrict__ w2b) {
    int idx = blockIdx.x * 256 + threadIdx.x;     // n*4096 + k
    int n = idx >> 12;
    w2b[idx] = __float2bfloat16(n < 50 ? fc2_w[idx] : 0.f);
}

// ---------------------------------------------------------------------------
__global__ void gt_kernel(const float* __restrict__ char_emb,
                          const float* __restrict__ conv_w,
                          float* __restrict__ gt) {
    int idx = blockIdx.x * 256 + threadIdx.x;     // < 19200
    if (idx >= 19200) return;
    int c = idx / 150, rem = idx - c * 150;
    int kk = rem / 50, o = rem - kk * 50;
    const float* ce = char_emb + c * 50;
    const float* w  = conv_w + o * 150 + kk;
    float s = 0.f;
    #pragma unroll 10
    for (int i = 0; i < 50; ++i) s += ce[i] * w[i * 3];
    gt[c * 156 + kk * 52 + o] = s;
}

// ---------------------------------------------------------------------------
__global__ void haPad_kernel(__hip_bfloat16* __restrict__ ha) {
    int idx = blockIdx.x * 256 + threadIdx.x;     // b*6 + j
    int b = idx / 6, j = idx - b * 6;
    ha[b * 256 + 250 + j] = __float2bfloat16(j == 0 ? 1.f : 0.f);
}

// ---------------------------------------------------------------------------
// conv via table lookup (unchanged, proven R7). Block = 512 thr = 32 words.
// ---------------------------------------------------------------------------
__global__ __launch_bounds__(512) void conv_kernel(
    const int* __restrict__ x, const int* __restrict__ wci,
    const float* __restrict__ word_emb, const float* __restrict__ conv_b,
    const float* __restrict__ gt, __hip_bfloat16* __restrict__ ha)
{
    __shared__ float Gs[19968];       // 79,872 B
    __shared__ uint  cpack[160];
    __shared__ int   xs[32];

    const int tid = threadIdx.x;
    const int gw0 = blockIdx.x * 32;

    int xr = 0;
    if (tid < 32) xr = x[gw0 + tid];

    #pragma unroll
    for (int t = 0; t < 39; ++t)
        Gs[t * 512 + tid] = gt[t * 512 + tid];

    if (tid < 32) {
        const int* crow = wci + xr * 20;
        int cid[20];
        #pragma unroll
        for (int p = 0; p < 20; ++p) cid[p] = crow[p];
        #pragma unroll
        for (int u = 0; u < 5; ++u)
            cpack[tid * 5 + u] = (uint)cid[u * 4] | ((uint)cid[u * 4 + 1] << 8)
                               | ((uint)cid[u * 4 + 2] << 16) | ((uint)cid[u * 4 + 3] << 24);
        xs[tid] = xr;
    }
    __syncthreads();

    const int lane = tid & 63;
    const int wv   = tid >> 6;
    const int t    = lane & 15;
    const int w    = lane >> 4;
    const int tc   = (t < 13) ? t : 12;
    const int widx = wv * 4 + w;

    uint cw[5];
    #pragma unroll
    for (int u = 0; u < 5; ++u) cw[u] = cpack[widx * 5 + u];
    int ca[20];
    #pragma unroll
    for (int p = 0; p < 20; ++p)
        ca[p] = (int)((cw[p >> 2] >> ((p & 3) * 8)) & 0xFF) * 156;

    const int tc4 = tc * 4;
    float4 mx;
    {
        float4 v = *(const float4*)&Gs[ca[0] + 52 + tc4];
        float4 u = *(const float4*)&Gs[ca[1] + 104 + tc4];
        mx.x = v.x + u.x; mx.y = v.y + u.y; mx.z = v.z + u.z; mx.w = v.w + u.w;
    }
    #pragma unroll
    for (int l = 1; l < 19; ++l) {
        float4 v = *(const float4*)&Gs[ca[l] + 52 + tc4];
        float4 a = *(const float4*)&Gs[ca[l - 1] + tc4];
        float4 b = *(const float4*)&Gs[ca[l + 1] + 104 + tc4];
        float vx = v.x + a.x + b.x, vy = v.y + a.y + b.y;
        float vz = v.z + a.z + b.z, vw = v.w + a.w + b.w;
        mx.x = fmaxf(mx.x, vx); mx.y = fmaxf(mx.y, vy);
        mx.z = fmaxf(mx.z, vz); mx.w = fmaxf(mx.w, vw);
    }
    {
        float4 v = *(const float4*)&Gs[ca[19] + 52 + tc4];
        float4 a = *(const float4*)&Gs[ca[18] + tc4];
        mx.x = fmaxf(mx.x, v.x + a.x); mx.y = fmaxf(mx.y, v.y + a.y);
        mx.z = fmaxf(mx.z, v.z + a.z); mx.w = fmaxf(mx.w, v.w + a.w);
    }

    const int xid = xs[widx];
    const float* wer = word_emb + (size_t)xid * 50 + tc4;
    float2 wea = *(const float2*)wer;
    float2 web = make_float2(0.f, 0.f);
    float2 cba = *(const float2*)(conv_b + tc4);
    float2 cbb = make_float2(0.f, 0.f);
    if (tc < 12) {
        web = *(const float2*)(wer + 2);
        cbb = *(const float2*)(conv_b + tc4 + 2);
    }
    const int gw = gw0 + widx, b = gw / 5, wp = gw - b * 5;
    __hip_bfloat16* dst = ha + b * 256 + wp * 50 + tc4;
    uint lo = packbf2(mx.x + cba.x + wea.x, mx.y + cba.y + wea.y);
    if (t < 12) {
        uint hi = packbf2(mx.z + cbb.x + web.x, mx.w + cbb.y + web.y);
        *(uint*)dst = lo;
        *((uint*)dst + 1) = hi;
    } else if (t == 12) {
        *(uint*)dst = lo;
    }
}

// ---------------------------------------------------------------------------
// FUSED fc1+tanh+fc2+softmax, latency-hiding restructure of proven R12 math.
// Block = 32 rows, 512 thr (8 waves). fc1: wave wv = col-tile (16 h-cols),
// computes both row-tiles; wb/w2b fragments register-prefetched per chunk.
// fc2: wave = (rt=wv>>2, nt=wv&3). Pack mapping = R12's (re-parametrized).
// ---------------------------------------------------------------------------
__global__ __launch_bounds__(512) void fused_kernel(
    const __hip_bfloat16* __restrict__ ha, const __hip_bfloat16* __restrict__ wb,
    const __hip_bfloat16* __restrict__ w2b, const float* __restrict__ fc2_b,
    float* __restrict__ out)
{
    __shared__ short8 As[1024];     // ha frags [(rt*8+ks)*64+lane], 16 KB
    __shared__ short8 Pf[512];      // P chunk as fc2 A-frags [(rt*4+ks2)*64+lane], 8 KB
    __shared__ float  Ls[32 * 68];  // logits, 8.7 KB

    const int tid  = threadIdx.x;
    const int lane = tid & 63;
    const int wv   = tid >> 6;
    const int m = lane & 15, q = lane >> 4;
    const int r0 = blockIdx.x * 32;
    const int rt2 = wv >> 2, nt2 = wv & 3;   // fc2 wave role

    // ---- stage ha rows once (K=256), proven frag-linear layout ----
    #pragma unroll
    for (int s = 0; s < 2; ++s) {
        const int seg = s * 512 + tid;            // 0..1023
        const int grp = seg >> 6;                 // rt*8 + ks
        const int rt = grp >> 3, ks = grp & 7;
        const int l = seg & 63;
        As[seg] = *(const short8*)(ha + (size_t)(r0 + rt * 16 + (l & 15)) * 256
                                      + ks * 32 + (l >> 4) * 8);
    }
    __syncthreads();

    float4v acc2 = {};

    for (int ch = 0; ch < 32; ++ch) {
        const int c0 = ch * 128;

        // ---- register prefetch: 8 wb frags (this wave's col-tile) + 4 w2b ----
        short8 av[8];
        #pragma unroll
        for (int ks = 0; ks < 8; ++ks)
            av[ks] = *(const short8*)(wb + (size_t)(c0 + wv * 16 + m) * 256
                                         + ks * 32 + q * 8);
        short8 bw2[4];
        #pragma unroll
        for (int ks2 = 0; ks2 < 4; ++ks2)
            bw2[ks2] = *(const short8*)(w2b + (size_t)(nt2 * 16 + m) * 4096
                                            + c0 + ks2 * 32 + q * 8);

        // ---- fc1: D rows = h-cols (wv*16 + q*4+r), D cols = ha-rows (m) ----
        float4v acc[2] = {};
        #pragma unroll
        for (int ks = 0; ks < 8; ++ks) {
            #pragma unroll
            for (int rt = 0; rt < 2; ++rt)
                acc[rt] = __builtin_amdgcn_mfma_f32_16x16x32_bf16(
                    av[ks], As[(rt * 8 + ks) * 64 + lane], acc[rt], 0, 0, 0);
        }
        __syncthreads();   // prior chunk's fc2 Pf reads complete

        // ---- tanh + pack into fc2 A-frag layout (one b64 per rt) ----
        #pragma unroll
        for (int rt = 0; rt < 2; ++rt) {
            float tv[4];
            #pragma unroll
            for (int r = 0; r < 4; ++r)
                tv[r] = 1.f - 2.f / (__expf(2.f * acc[rt][r]) + 1.f);
            const uint p0 = packbf2(tv[0], tv[1]);
            const uint p1 = packbf2(tv[2], tv[3]);
            const int seg = (rt * 4 + (wv >> 1)) * 64
                          + ((wv & 1) * 2 + (q >> 1)) * 16 + m;
            *(uint2*)((char*)&Pf[seg] + (q & 1) * 8) = make_uint2(p0, p1);
        }
        __syncthreads();   // Pf visible

        // ---- fc2: accumulate logits (A=Pf rows, B=w2b classes) ----
        #pragma unroll
        for (int ks2 = 0; ks2 < 4; ++ks2)
            acc2 = __builtin_amdgcn_mfma_f32_16x16x32_bf16(
                Pf[(rt2 * 4 + ks2) * 64 + lane], bw2[ks2], acc2, 0, 0, 0);
    }

    // ---- logits -> LDS (C layout: row=q*4+r, col=m) ----
    #pragma unroll
    for (int r = 0; r < 4; ++r)
        Ls[(rt2 * 16 + q * 4 + r) * 68 + nt2 * 16 + m] = acc2[r];
    __syncthreads();

    // ---- softmax: 4 rows per wave (proven shuffle pattern) ----
    #pragma unroll
    for (int rr = 0; rr < 4; ++rr) {
        const int row = wv * 4 + rr;
        float v = (lane < 50) ? Ls[row * 68 + lane] + fc2_b[lane] : -1e30f;
        float mx = v;
        for (int off = 32; off > 0; off >>= 1) mx = fmaxf(mx, __shfl_xor(mx, off));
        float e = __expf(v - mx);
        float ssum = e;
        for (int off = 32; off > 0; off >>= 1) ssum += __shfl_xor(ssum, off);
        if (lane < 50)
            out[(size_t)(r0 + row) * 50 + lane] = e / ssum;
    }
}

// ---------------------------------------------------------------------------
extern "C" void kernel_launch(void* const* d_in, const int* in_sizes, int n_in,
                              void* d_out, int out_size, void* d_ws, size_t ws_size,
                              hipStream_t stream) {
    const int*   x        = (const int*)  d_in[0];
    const int*   wci      = (const int*)  d_in[1];
    const float* word_emb = (const float*)d_in[2];
    const float* char_emb = (const float*)d_in[3];
    const float* conv_w   = (const float*)d_in[4];
    const float* conv_b   = (const float*)d_in[5];
    const float* fc1_w    = (const float*)d_in[6];
    const float* fc1_b    = (const float*)d_in[7];
    const float* fc2_w    = (const float*)d_in[8];
    const float* fc2_b    = (const float*)d_in[9];
    float* out = (float*)d_out;

    char* ws = (char*)d_ws;
    __hip_bfloat16* ha  = (__hip_bfloat16*)ws;                          // 8 MB
    __hip_bfloat16* wb  = (__hip_bfloat16*)(ws + ((size_t)8  << 20));   // 2 MB
    __hip_bfloat16* w2b = (__hip_bfloat16*)(ws + ((size_t)10 << 20));   // 0.5 MB
    float*          gtp = (float*)(ws + ((size_t)16 << 20));            // 78 KB

    wb_kernel<<<4096, 256, 0, stream>>>(fc1_w, fc1_b, wb);
    w2b_kernel<<<1024, 256, 0, stream>>>(fc2_w, w2b);
    gt_kernel<<<75, 256, 0, stream>>>(char_emb, conv_w, gtp);
    haPad_kernel<<<384, 256, 0, stream>>>(ha);
    conv_kernel<<<2560, 512, 0, stream>>>(x, wci, word_emb, conv_b, gtp, ha);
    fused_kernel<<<512, 512, 0, stream>>>(ha, wb, w2b, fc2_b, out);
}

// Round 14
// 308.849 us; speedup vs baseline: 1.5629x; 1.0007x over previous
//
#include <hip/hip_runtime.h>
#include <hip/hip_bf16.h>

// B=16384 W=5 L=20 E=50 V=100000 C=128 H=4096 O=50
// ha  = bf16 [16384][256] (K: 250 data + [250]=1.0 bias slot + pad)  ws+0    (8 MB)
// wb  = bf16 [4096][256]  (fc1_w as [N][K], [n][250]=fc1_b[n])       ws+8M   (2 MB)
// w2b = bf16 [64][4096]   (fc2_w padded to 64 rows)                  ws+10M  (0.5 MB)
// gt  = fp32 [128][156]                                              ws+16M  (78 KB)
// h never materialized. Fused kernel: 32 rows/block, 512 blocks,
// software-pipelined register prefetch (launch_bounds(512,4) -> VGPR<=128),
// double-buffered Pf -> ONE barrier per chunk.

typedef __attribute__((ext_vector_type(8))) short short8;
typedef __attribute__((ext_vector_type(4))) float float4v;

__device__ inline short bf16b(float f) {
    __hip_bfloat16 h = __float2bfloat16(f);
    return *reinterpret_cast<short*>(&h);
}
__device__ inline uint packbf2(float a, float b) {
    return (uint)(ushort)bf16b(a) | ((uint)(ushort)bf16b(b) << 16);
}

// ---------------------------------------------------------------------------
__global__ void wb_kernel(const float* __restrict__ fc1_w,
                          const float* __restrict__ fc1_b,
                          __hip_bfloat16* __restrict__ wb) {
    int idx = blockIdx.x * 256 + threadIdx.x;     // n*256 + k
    int n = idx >> 8, k = idx & 255;
    float v = (k < 250) ? fc1_w[n * 250 + k] : (k == 250 ? fc1_b[n] : 0.f);
    wb[idx] = __float2bfloat16(v);
}

// ---------------------------------------------------------------------------
__global__ void w2b_kernel(const float* __restrict__ fc2_w,
                           __hip_bfloat16* __restrict__ w2b) {
    int idx = blockIdx.x * 256 + threadIdx.x;     // n*4096 + k
    int n = idx >> 12;
    w2b[idx] = __float2bfloat16(n < 50 ? fc2_w[idx] : 0.f);
}

// ---------------------------------------------------------------------------
__global__ void gt_kernel(const float* __restrict__ char_emb,
                          const float* __restrict__ conv_w,
                          float* __restrict__ gt) {
    int idx = blockIdx.x * 256 + threadIdx.x;     // < 19200
    if (idx >= 19200) return;
    int c = idx / 150, rem = idx - c * 150;
    int kk = rem / 50, o = rem - kk * 50;
    const float* ce = char_emb + c * 50;
    const float* w  = conv_w + o * 150 + kk;
    float s = 0.f;
    #pragma unroll 10
    for (int i = 0; i < 50; ++i) s += ce[i] * w[i * 3];
    gt[c * 156 + kk * 52 + o] = s;
}

// ---------------------------------------------------------------------------
__global__ void haPad_kernel(__hip_bfloat16* __restrict__ ha) {
    int idx = blockIdx.x * 256 + threadIdx.x;     // b*6 + j
    int b = idx / 6, j = idx - b * 6;
    ha[b * 256 + 250 + j] = __float2bfloat16(j == 0 ? 1.f : 0.f);
}

// ---------------------------------------------------------------------------
// conv via table lookup (unchanged, proven R7). Block = 512 thr = 32 words.
// ---------------------------------------------------------------------------
__global__ __launch_bounds__(512) void conv_kernel(
    const int* __restrict__ x, const int* __restrict__ wci,
    const float* __restrict__ word_emb, const float* __restrict__ conv_b,
    const float* __restrict__ gt, __hip_bfloat16* __restrict__ ha)
{
    __shared__ float Gs[19968];       // 79,872 B
    __shared__ uint  cpack[160];
    __shared__ int   xs[32];

    const int tid = threadIdx.x;
    const int gw0 = blockIdx.x * 32;

    int xr = 0;
    if (tid < 32) xr = x[gw0 + tid];

    #pragma unroll
    for (int t = 0; t < 39; ++t)
        Gs[t * 512 + tid] = gt[t * 512 + tid];

    if (tid < 32) {
        const int* crow = wci + xr * 20;
        int cid[20];
        #pragma unroll
        for (int p = 0; p < 20; ++p) cid[p] = crow[p];
        #pragma unroll
        for (int u = 0; u < 5; ++u)
            cpack[tid * 5 + u] = (uint)cid[u * 4] | ((uint)cid[u * 4 + 1] << 8)
                               | ((uint)cid[u * 4 + 2] << 16) | ((uint)cid[u * 4 + 3] << 24);
        xs[tid] = xr;
    }
    __syncthreads();

    const int lane = tid & 63;
    const int wv   = tid >> 6;
    const int t    = lane & 15;
    const int w    = lane >> 4;
    const int tc   = (t < 13) ? t : 12;
    const int widx = wv * 4 + w;

    uint cw[5];
    #pragma unroll
    for (int u = 0; u < 5; ++u) cw[u] = cpack[widx * 5 + u];
    int ca[20];
    #pragma unroll
    for (int p = 0; p < 20; ++p)
        ca[p] = (int)((cw[p >> 2] >> ((p & 3) * 8)) & 0xFF) * 156;

    const int tc4 = tc * 4;
    float4 mx;
    {
        float4 v = *(const float4*)&Gs[ca[0] + 52 + tc4];
        float4 u = *(const float4*)&Gs[ca[1] + 104 + tc4];
        mx.x = v.x + u.x; mx.y = v.y + u.y; mx.z = v.z + u.z; mx.w = v.w + u.w;
    }
    #pragma unroll
    for (int l = 1; l < 19; ++l) {
        float4 v = *(const float4*)&Gs[ca[l] + 52 + tc4];
        float4 a = *(const float4*)&Gs[ca[l - 1] + tc4];
        float4 b = *(const float4*)&Gs[ca[l + 1] + 104 + tc4];
        float vx = v.x + a.x + b.x, vy = v.y + a.y + b.y;
        float vz = v.z + a.z + b.z, vw = v.w + a.w + b.w;
        mx.x = fmaxf(mx.x, vx); mx.y = fmaxf(mx.y, vy);
        mx.z = fmaxf(mx.z, vz); mx.w = fmaxf(mx.w, vw);
    }
    {
        float4 v = *(const float4*)&Gs[ca[19] + 52 + tc4];
        float4 a = *(const float4*)&Gs[ca[18] + tc4];
        mx.x = fmaxf(mx.x, v.x + a.x); mx.y = fmaxf(mx.y, v.y + a.y);
        mx.z = fmaxf(mx.z, v.z + a.z); mx.w = fmaxf(mx.w, v.w + a.w);
    }

    const int xid = xs[widx];
    const float* wer = word_emb + (size_t)xid * 50 + tc4;
    float2 wea = *(const float2*)wer;
    float2 web = make_float2(0.f, 0.f);
    float2 cba = *(const float2*)(conv_b + tc4);
    float2 cbb = make_float2(0.f, 0.f);
    if (tc < 12) {
        web = *(const float2*)(wer + 2);
        cbb = *(const float2*)(conv_b + tc4 + 2);
    }
    const int gw = gw0 + widx, b = gw / 5, wp = gw - b * 5;
    __hip_bfloat16* dst = ha + b * 256 + wp * 50 + tc4;
    uint lo = packbf2(mx.x + cba.x + wea.x, mx.y + cba.y + wea.y);
    if (t < 12) {
        uint hi = packbf2(mx.z + cbb.x + web.x, mx.w + cbb.y + web.y);
        *(uint*)dst = lo;
        *((uint*)dst + 1) = hi;
    } else if (t == 12) {
        *(uint*)dst = lo;
    }
}

// ---------------------------------------------------------------------------
// FUSED fc1+tanh+fc2+softmax. All layout math identical to passing R13.
// New: launch_bounds(512,4) (VGPR cap 128, 2 blocks/CU), software-pipelined
// av prefetch (next chunk in flight during current MFMA), bw2 issued early,
// Pf double-buffered -> single barrier per chunk.
// ---------------------------------------------------------------------------
__global__ __launch_bounds__(512, 4) void fused_kernel(
    const __hip_bfloat16* __restrict__ ha, const __hip_bfloat16* __restrict__ wb,
    const __hip_bfloat16* __restrict__ w2b, const float* __restrict__ fc2_b,
    float* __restrict__ out)
{
    __shared__ short8 As[1024];     // ha frags [(rt*8+ks)*64+lane], 16 KB
    __shared__ short8 Pf[2][512];   // P chunk as fc2 A-frags, double-buffered, 16 KB
    __shared__ float  Ls[32 * 68];  // logits, 8.7 KB

    const int tid  = threadIdx.x;
    const int lane = tid & 63;
    const int wv   = tid >> 6;
    const int m = lane & 15, q = lane >> 4;
    const int r0 = blockIdx.x * 32;
    const int rt2 = wv >> 2, nt2 = wv & 3;   // fc2 wave role

    // ---- stage ha rows once (K=256), proven frag-linear layout ----
    #pragma unroll
    for (int s = 0; s < 2; ++s) {
        const int seg = s * 512 + tid;            // 0..1023
        const int grp = seg >> 6;                 // rt*8 + ks
        const int rt = grp >> 3, ks = grp & 7;
        const int l = seg & 63;
        As[seg] = *(const short8*)(ha + (size_t)(r0 + rt * 16 + (l & 15)) * 256
                                      + ks * 32 + (l >> 4) * 8);
    }
    __syncthreads();

    // per-thread base pointers (chunk advances by constant offsets)
    const __hip_bfloat16* wbp  = wb  + (size_t)(wv * 16 + m) * 256 + q * 8;
    const __hip_bfloat16* w2bp = w2b + (size_t)(nt2 * 16 + m) * 4096 + q * 8;

    // preload chunk 0's wb fragments
    short8 avc[8], avn[8];
    #pragma unroll
    for (int ks = 0; ks < 8; ++ks)
        avc[ks] = *(const short8*)(wbp + ks * 32);

    float4v acc2 = {};

    for (int ch = 0; ch < 32; ++ch) {
        // ---- issue next chunk's av + this chunk's bw2 (in flight under MFMA) ----
        if (ch < 31) {
            const size_t nof = (size_t)(ch + 1) * 32768;   // 128 rows * 256 cols
            #pragma unroll
            for (int ks = 0; ks < 8; ++ks)
                avn[ks] = *(const short8*)(wbp + nof + ks * 32);
        }
        short8 bw2[4];
        {
            const size_t cof = (size_t)ch * 128;
            #pragma unroll
            for (int ks2 = 0; ks2 < 4; ++ks2)
                bw2[ks2] = *(const short8*)(w2bp + cof + ks2 * 32);
        }

        // ---- fc1: D rows = h-cols (wv*16 + q*4+r), D cols = ha-rows (m) ----
        float4v acc[2] = {};
        #pragma unroll
        for (int ks = 0; ks < 8; ++ks) {
            #pragma unroll
            for (int rt = 0; rt < 2; ++rt)
                acc[rt] = __builtin_amdgcn_mfma_f32_16x16x32_bf16(
                    avc[ks], As[(rt * 8 + ks) * 64 + lane], acc[rt], 0, 0, 0);
        }

        // ---- tanh + pack into fc2 A-frag layout (buffer ch&1) ----
        short8* pf = Pf[ch & 1];
        #pragma unroll
        for (int rt = 0; rt < 2; ++rt) {
            float tv[4];
            #pragma unroll
            for (int r = 0; r < 4; ++r)
                tv[r] = 1.f - 2.f / (__expf(2.f * acc[rt][r]) + 1.f);
            const uint p0 = packbf2(tv[0], tv[1]);
            const uint p1 = packbf2(tv[2], tv[3]);
            const int seg = (rt * 4 + (wv >> 1)) * 64
                          + ((wv & 1) * 2 + (q >> 1)) * 16 + m;
            *(uint2*)((char*)&pf[seg] + (q & 1) * 8) = make_uint2(p0, p1);
        }
        __syncthreads();   // pf visible; also orders reuse of this buffer (2-chunk gap)

        // ---- fc2: accumulate logits (A=Pf rows, B=w2b classes) ----
        #pragma unroll
        for (int ks2 = 0; ks2 < 4; ++ks2)
            acc2 = __builtin_amdgcn_mfma_f32_16x16x32_bf16(
                pf[(rt2 * 4 + ks2) * 64 + lane], bw2[ks2], acc2, 0, 0, 0);

        // ---- rotate prefetched fragments ----
        #pragma unroll
        for (int ks = 0; ks < 8; ++ks) avc[ks] = avn[ks];
    }

    // ---- logits -> LDS (C layout: row=q*4+r, col=m) ----
    #pragma unroll
    for (int r = 0; r < 4; ++r)
        Ls[(rt2 * 16 + q * 4 + r) * 68 + nt2 * 16 + m] = acc2[r];
    __syncthreads();

    // ---- softmax: 4 rows per wave (proven shuffle pattern) ----
    #pragma unroll
    for (int rr = 0; rr < 4; ++rr) {
        const int row = wv * 4 + rr;
        float v = (lane < 50) ? Ls[row * 68 + lane] + fc2_b[lane] : -1e30f;
        float mx = v;
        for (int off = 32; off > 0; off >>= 1) mx = fmaxf(mx, __shfl_xor(mx, off));
        float e = __expf(v - mx);
        float ssum = e;
        for (int off = 32; off > 0; off >>= 1) ssum += __shfl_xor(ssum, off);
        if (lane < 50)
            out[(size_t)(r0 + row) * 50 + lane] = e / ssum;
    }
}

// ---------------------------------------------------------------------------
extern "C" void kernel_launch(void* const* d_in, const int* in_sizes, int n_in,
                              void* d_out, int out_size, void* d_ws, size_t ws_size,
                              hipStream_t stream) {
    const int*   x        = (const int*)  d_in[0];
    const int*   wci      = (const int*)  d_in[1];
    const float* word_emb = (const float*)d_in[2];
    const float* char_emb = (const float*)d_in[3];
    const float* conv_w   = (const float*)d_in[4];
    const float* conv_b   = (const float*)d_in[5];
    const float* fc1_w    = (const float*)d_in[6];
    const float* fc1_b    = (const float*)d_in[7];
    const float* fc2_w    = (const float*)d_in[8];
    const float* fc2_b    = (const float*)d_in[9];
    float* out = (float*)d_out;

    char* ws = (char*)d_ws;
    __hip_bfloat16* ha  = (__hip_bfloat16*)ws;                          // 8 MB
    __hip_bfloat16* wb  = (__hip_bfloat16*)(ws + ((size_t)8  << 20));   // 2 MB
    __hip_bfloat16* w2b = (__hip_bfloat16*)(ws + ((size_t)10 << 20));   // 0.5 MB
    float*          gtp = (float*)(ws + ((size_t)16 << 20));            // 78 KB

    wb_kernel<<<4096, 256, 0, stream>>>(fc1_w, fc1_b, wb);
    w2b_kernel<<<1024, 256, 0, stream>>>(fc2_w, w2b);
    gt_kernel<<<75, 256, 0, stream>>>(char_emb, conv_w, gtp);
    haPad_kernel<<<384, 256, 0, stream>>>(ha);
    conv_kernel<<<2560, 512, 0, stream>>>(x, wci, word_emb, conv_b, gtp, ha);
    fused_kernel<<<512, 512, 0, stream>>>(ha, wb, w2b, fc2_b, out);
}

// Round 15
// 261.567 us; speedup vs baseline: 1.8454x; 1.1808x over previous
//
#include <hip/hip_runtime.h>
#include <hip/hip_bf16.h>

// B=16384 W=5 L=20 E=50 V=100000 C=128 H=4096 O=50
// ha  = bf16 [16384][256] (K: 250 data + [250]=1.0 bias + pad)   ws+0    (8 MB)
// wb  = bf16 [4096][256]  (fc1_w as [N][K], [n][250]=fc1_b[n])   ws+8M   (2 MB)
// w2b = bf16 [64][4096]   (fc2_w padded to 64 rows)              ws+10M  (0.5 MB)
// hf  = h in fc2-A-FRAGMENT layout: short8 frag at index         ws+16M  (128 MB)
//       (R*128 + ks2)*64 + q2*16 + m  == rows R*16+m, cols ks2*32+q2*8..+7
// gt  = fp32 [128][156]                                          ws+144M (78 KB)

typedef __attribute__((ext_vector_type(8))) short short8;
typedef __attribute__((ext_vector_type(4))) float float4v;

__device__ inline short bf16b(float f) {
    __hip_bfloat16 h = __float2bfloat16(f);
    return *reinterpret_cast<short*>(&h);
}
__device__ inline uint packbf2(float a, float b) {
    return (uint)(ushort)bf16b(a) | ((uint)(ushort)bf16b(b) << 16);
}

// ---------------------------------------------------------------------------
__global__ void wb_kernel(const float* __restrict__ fc1_w,
                          const float* __restrict__ fc1_b,
                          __hip_bfloat16* __restrict__ wb) {
    int idx = blockIdx.x * 256 + threadIdx.x;     // n*256 + k
    int n = idx >> 8, k = idx & 255;
    float v = (k < 250) ? fc1_w[n * 250 + k] : (k == 250 ? fc1_b[n] : 0.f);
    wb[idx] = __float2bfloat16(v);
}

// ---------------------------------------------------------------------------
__global__ void w2b_kernel(const float* __restrict__ fc2_w,
                           __hip_bfloat16* __restrict__ w2b) {
    int idx = blockIdx.x * 256 + threadIdx.x;     // n*4096 + k
    int n = idx >> 12;
    w2b[idx] = __float2bfloat16(n < 50 ? fc2_w[idx] : 0.f);
}

// ---------------------------------------------------------------------------
__global__ void gt_kernel(const float* __restrict__ char_emb,
                          const float* __restrict__ conv_w,
                          float* __restrict__ gt) {
    int idx = blockIdx.x * 256 + threadIdx.x;     // < 19200
    if (idx >= 19200) return;
    int c = idx / 150, rem = idx - c * 150;
    int kk = rem / 50, o = rem - kk * 50;
    const float* ce = char_emb + c * 50;
    const float* w  = conv_w + o * 150 + kk;
    float s = 0.f;
    #pragma unroll 10
    for (int i = 0; i < 50; ++i) s += ce[i] * w[i * 3];
    gt[c * 156 + kk * 52 + o] = s;
}

// ---------------------------------------------------------------------------
__global__ void haPad_kernel(__hip_bfloat16* __restrict__ ha) {
    int idx = blockIdx.x * 256 + threadIdx.x;     // b*6 + j
    int b = idx / 6, j = idx - b * 6;
    ha[b * 256 + 250 + j] = __float2bfloat16(j == 0 ? 1.f : 0.f);
}

// ---------------------------------------------------------------------------
// conv via table lookup (unchanged, proven R7). Block = 512 thr = 32 words.
// ---------------------------------------------------------------------------
__global__ __launch_bounds__(512) void conv_kernel(
    const int* __restrict__ x, const int* __restrict__ wci,
    const float* __restrict__ word_emb, const float* __restrict__ conv_b,
    const float* __restrict__ gt, __hip_bfloat16* __restrict__ ha)
{
    __shared__ float Gs[19968];       // 79,872 B
    __shared__ uint  cpack[160];
    __shared__ int   xs[32];

    const int tid = threadIdx.x;
    const int gw0 = blockIdx.x * 32;

    int xr = 0;
    if (tid < 32) xr = x[gw0 + tid];

    #pragma unroll
    for (int t = 0; t < 39; ++t)
        Gs[t * 512 + tid] = gt[t * 512 + tid];

    if (tid < 32) {
        const int* crow = wci + xr * 20;
        int cid[20];
        #pragma unroll
        for (int p = 0; p < 20; ++p) cid[p] = crow[p];
        #pragma unroll
        for (int u = 0; u < 5; ++u)
            cpack[tid * 5 + u] = (uint)cid[u * 4] | ((uint)cid[u * 4 + 1] << 8)
                               | ((uint)cid[u * 4 + 2] << 16) | ((uint)cid[u * 4 + 3] << 24);
        xs[tid] = xr;
    }
    __syncthreads();

    const int lane = tid & 63;
    const int wv   = tid >> 6;
    const int t    = lane & 15;
    const int w    = lane >> 4;
    const int tc   = (t < 13) ? t : 12;
    const int widx = wv * 4 + w;

    uint cw[5];
    #pragma unroll
    for (int u = 0; u < 5; ++u) cw[u] = cpack[widx * 5 + u];
    int ca[20];
    #pragma unroll
    for (int p = 0; p < 20; ++p)
        ca[p] = (int)((cw[p >> 2] >> ((p & 3) * 8)) & 0xFF) * 156;

    const int tc4 = tc * 4;
    float4 mx;
    {
        float4 v = *(const float4*)&Gs[ca[0] + 52 + tc4];
        float4 u = *(const float4*)&Gs[ca[1] + 104 + tc4];
        mx.x = v.x + u.x; mx.y = v.y + u.y; mx.z = v.z + u.z; mx.w = v.w + u.w;
    }
    #pragma unroll
    for (int l = 1; l < 19; ++l) {
        float4 v = *(const float4*)&Gs[ca[l] + 52 + tc4];
        float4 a = *(const float4*)&Gs[ca[l - 1] + tc4];
        float4 b = *(const float4*)&Gs[ca[l + 1] + 104 + tc4];
        float vx = v.x + a.x + b.x, vy = v.y + a.y + b.y;
        float vz = v.z + a.z + b.z, vw = v.w + a.w + b.w;
        mx.x = fmaxf(mx.x, vx); mx.y = fmaxf(mx.y, vy);
        mx.z = fmaxf(mx.z, vz); mx.w = fmaxf(mx.w, vw);
    }
    {
        float4 v = *(const float4*)&Gs[ca[19] + 52 + tc4];
        float4 a = *(const float4*)&Gs[ca[18] + tc4];
        mx.x = fmaxf(mx.x, v.x + a.x); mx.y = fmaxf(mx.y, v.y + a.y);
        mx.z = fmaxf(mx.z, v.z + a.z); mx.w = fmaxf(mx.w, v.w + a.w);
    }

    const int xid = xs[widx];
    const float* wer = word_emb + (size_t)xid * 50 + tc4;
    float2 wea = *(const float2*)wer;
    float2 web = make_float2(0.f, 0.f);
    float2 cba = *(const float2*)(conv_b + tc4);
    float2 cbb = make_float2(0.f, 0.f);
    if (tc < 12) {
        web = *(const float2*)(wer + 2);
        cbb = *(const float2*)(conv_b + tc4 + 2);
    }
    const int gw = gw0 + widx, b = gw / 5, wp = gw - b * 5;
    __hip_bfloat16* dst = ha + b * 256 + wp * 50 + tc4;
    uint lo = packbf2(mx.x + cba.x + wea.x, mx.y + cba.y + wea.y);
    if (t < 12) {
        uint hi = packbf2(mx.z + cbb.x + web.x, mx.w + cbb.y + web.y);
        *(uint*)dst = lo;
        *((uint*)dst + 1) = hi;
    } else if (t == 12) {
        *(uint*)dst = lo;
    }
}

// ---------------------------------------------------------------------------
// FC1 bf16 MFMA: R10/R11-proven 128x128 tile, BK=64, per-lane LDS staging.
// MFMA operand-swapped (D-rows = h-cols) + tanh + pack -> hf in fc2-A-frag
// layout via coalesced 8B stores. Pack algebra = R12/R13/R14-passed mapping.
// ---------------------------------------------------------------------------
__global__ __launch_bounds__(256) void fc1_kernel(
    const __hip_bfloat16* __restrict__ ha, const __hip_bfloat16* __restrict__ wb,
    short* __restrict__ hf)
{
    __shared__ short8 As[1024];   // [(ks*8+mt)*64 + lane]  16 KB
    __shared__ short8 Bs[1024];   // 16 KB
    const int tid  = threadIdx.x;
    const int lane = tid & 63;
    const int wv   = tid >> 6;
    const int wm = wv >> 1, wn = wv & 1;
    const int m0 = blockIdx.x * 128;      // ha rows
    const int n0 = blockIdx.y * 128;      // h cols (wb rows)

    float4v acc[4][4] = {};

    for (int kt = 0; kt < 4; ++kt) {
        const int k0 = kt * 64;
        #pragma unroll
        for (int s = 0; s < 4; ++s) {
            const int seg = s * 256 + tid;        // 0..1023
            const int grp = seg >> 6;             // ks*8 + mt
            const int ks = grp >> 3, mt = grp & 7;
            const int l = seg & 63;
            const int q = l >> 4, mm = l & 15;
            As[seg] = *(const short8*)(ha + (size_t)(m0 + mt * 16 + mm) * 256
                                          + k0 + ks * 32 + q * 8);
            Bs[seg] = *(const short8*)(wb + (size_t)(n0 + mt * 16 + mm) * 256
                                          + k0 + ks * 32 + q * 8);
        }
        __syncthreads();
        #pragma unroll
        for (int ks = 0; ks < 2; ++ks) {
            short8 av[4], bv[4];
            #pragma unroll
            for (int t = 0; t < 4; ++t) {
                av[t] = As[(ks * 8 + wm * 4 + t) * 64 + lane];
                bv[t] = Bs[(ks * 8 + wn * 4 + t) * 64 + lane];
            }
            #pragma unroll
            for (int mt = 0; mt < 4; ++mt)
                #pragma unroll
                for (int nt = 0; nt < 4; ++nt)
                    acc[mt][nt] = __builtin_amdgcn_mfma_f32_16x16x32_bf16(
                        bv[nt], av[mt], acc[mt][nt], 0, 0, 0);   // swapped: D-rows = h-cols
        }
        __syncthreads();
    }

    // epilogue: tanh (bias folded via K) + pack to frag layout, coalesced 8B stores
    const int q = lane >> 4, m = lane & 15;
    const int q2base = q >> 1, slot = q & 1;
    #pragma unroll
    for (int mt = 0; mt < 4; ++mt) {
        const int R = blockIdx.x * 8 + wm * 4 + mt;      // row-tile (row = R*16+m)
        #pragma unroll
        for (int nt = 0; nt < 4; ++nt) {
            const int CT = blockIdx.y * 8 + wn * 4 + nt; // h-col tile (cols CT*16+q*4+r)
            float tv[4];
            #pragma unroll
            for (int r = 0; r < 4; ++r)
                tv[r] = 1.f - 2.f / (__expf(2.f * acc[mt][nt][r]) + 1.f);
            const uint p0 = packbf2(tv[0], tv[1]);
            const uint p1 = packbf2(tv[2], tv[3]);
            const int ks2 = CT >> 1;
            const int q2  = (CT & 1) * 2 + q2base;
            const size_t fidx = (size_t)(R * 128 + ks2) * 64 + q2 * 16 + m;
            *(uint2*)((char*)(hf + fidx * 8) + slot * 8) = make_uint2(p0, p1);
        }
    }
}

// ---------------------------------------------------------------------------
// FC2 bf16 MFMA + fused softmax (R11-proven body): 512 blocks x 32 rows,
// 4 waves K-split. av loads now from frag-layout hf (coalesced 16B).
// ---------------------------------------------------------------------------
__global__ __launch_bounds__(256) void fc2_kernel(
    const short* __restrict__ hf, const __hip_bfloat16* __restrict__ w2b,
    const float* __restrict__ fc2_b, float* __restrict__ out)
{
    __shared__ float part[4][32][64];
    const int tid  = threadIdx.x;
    const int lane = tid & 63;
    const int wv   = tid >> 6;
    const int rb = blockIdx.x * 32;     // global row base
    const int m = lane & 15, q = lane >> 4;

    float4v acc[2][4] = {};
    const int kbase = wv * 1024;

    for (int s = 0; s < 32; ++s) {
        const int kk = kbase + s * 32 + q * 8;
        short8 av[2], bv[4];
        #pragma unroll
        for (int mt = 0; mt < 2; ++mt)
            av[mt] = *(const short8*)(hf
                + ((size_t)((blockIdx.x * 2 + mt) * 128 + wv * 32 + s) * 64 + lane) * 8);
        #pragma unroll
        for (int nt = 0; nt < 4; ++nt)
            bv[nt] = *(const short8*)(w2b + (size_t)(nt * 16 + m) * 4096 + kk);
        #pragma unroll
        for (int mt = 0; mt < 2; ++mt)
            #pragma unroll
            for (int nt = 0; nt < 4; ++nt)
                acc[mt][nt] = __builtin_amdgcn_mfma_f32_16x16x32_bf16(
                    av[mt], bv[nt], acc[mt][nt], 0, 0, 0);
    }

    #pragma unroll
    for (int mt = 0; mt < 2; ++mt)
        #pragma unroll
        for (int nt = 0; nt < 4; ++nt)
            #pragma unroll
            for (int r = 0; r < 4; ++r)
                part[wv][mt * 16 + q * 4 + r][nt * 16 + m] = acc[mt][nt][r];
    __syncthreads();

    #pragma unroll
    for (int t = 0; t < 8; ++t) {
        int idx = t * 256 + tid;
        int row = idx >> 6, col = idx & 63;
        float lg = part[0][row][col] + part[1][row][col]
                 + part[2][row][col] + part[3][row][col];
        part[0][row][col] = (col < 50) ? lg + fc2_b[col] : -1e30f;
    }
    __syncthreads();

    #pragma unroll
    for (int rr = 0; rr < 8; ++rr) {
        const int row = wv * 8 + rr;
        float v = part[0][row][lane];
        float mx = v;
        for (int off = 32; off > 0; off >>= 1) mx = fmaxf(mx, __shfl_xor(mx, off));
        float e = __expf(v - mx);
        float ssum = e;
        for (int off = 32; off > 0; off >>= 1) ssum += __shfl_xor(ssum, off);
        if (lane < 50)
            out[(size_t)(rb + row) * 50 + lane] = e / ssum;
    }
}

// ---------------------------------------------------------------------------
extern "C" void kernel_launch(void* const* d_in, const int* in_sizes, int n_in,
                              void* d_out, int out_size, void* d_ws, size_t ws_size,
                              hipStream_t stream) {
    const int*   x        = (const int*)  d_in[0];
    const int*   wci      = (const int*)  d_in[1];
    const float* word_emb = (const float*)d_in[2];
    const float* char_emb = (const float*)d_in[3];
    const float* conv_w   = (const float*)d_in[4];
    const float* conv_b   = (const float*)d_in[5];
    const float* fc1_w    = (const float*)d_in[6];
    const float* fc1_b    = (const float*)d_in[7];
    const float* fc2_w    = (const float*)d_in[8];
    const float* fc2_b    = (const float*)d_in[9];
    float* out = (float*)d_out;

    char* ws = (char*)d_ws;
    __hip_bfloat16* ha  = (__hip_bfloat16*)ws;                          // 8 MB
    __hip_bfloat16* wb  = (__hip_bfloat16*)(ws + ((size_t)8  << 20));   // 2 MB
    __hip_bfloat16* w2b = (__hip_bfloat16*)(ws + ((size_t)10 << 20));   // 0.5 MB
    short*          hf  = (short*)(ws + ((size_t)16 << 20));            // 128 MB
    float*          gtp = (float*)(ws + ((size_t)144 << 20));           // 78 KB

    wb_kernel<<<4096, 256, 0, stream>>>(fc1_w, fc1_b, wb);
    w2b_kernel<<<1024, 256, 0, stream>>>(fc2_w, w2b);
    gt_kernel<<<75, 256, 0, stream>>>(char_emb, conv_w, gtp);
    haPad_kernel<<<384, 256, 0, stream>>>(ha);
    conv_kernel<<<2560, 512, 0, stream>>>(x, wci, word_emb, conv_b, gtp, ha);
    fc1_kernel<<<dim3(128, 32), 256, 0, stream>>>(ha, wb, hf);
    fc2_kernel<<<512, 256, 0, stream>>>(hf, w2b, fc2_b, out);
}